// Round 1
// baseline (709.060 us; speedup 1.0000x reference)
//
#include <hip/hip_runtime.h>
#include <hip/hip_bf16.h>

typedef __attribute__((ext_vector_type(8))) short short8;
typedef __attribute__((ext_vector_type(4))) float f32x4;
typedef __hip_bfloat16 bf16;

#define SEQ 2048
#define DIM 2048
#define NH 32
#define NKV 8
#define HD 64
#define QKVD 3072
#define KVD 512

__device__ inline void gld_lds16(const bf16* g, bf16* l) {
    __builtin_amdgcn_global_load_lds((const __attribute__((address_space(1))) void*)g,
                                     (__attribute__((address_space(3))) void*)l, 16, 0, 0);
}

__device__ inline void store_val(float* p, float v) { *p = v; }
__device__ inline void store_val(bf16* p, float v) { *p = __float2bfloat16(v); }

// ---------------- fp32 -> bf16 convert (vectorized) ----------------
__global__ void cvt_kernel(const float* __restrict__ in, bf16* __restrict__ out, int n4) {
    int i = blockIdx.x * blockDim.x + threadIdx.x;
    if (i < n4) {
        float4 v = ((const float4*)in)[i];
        ushort4 u;
        bf16 b0 = __float2bfloat16(v.x); u.x = *(unsigned short*)&b0;
        bf16 b1 = __float2bfloat16(v.y); u.y = *(unsigned short*)&b1;
        bf16 b2 = __float2bfloat16(v.z); u.z = *(unsigned short*)&b2;
        bf16 b3 = __float2bfloat16(v.w); u.w = *(unsigned short*)&b3;
        ((ushort4*)out)[i] = u;
    }
}

// ---------------- NT GEMM: C[M,N] = A[M,K] * Bt[N,K]^T  (m97 structure) ----------------
// 128x128 tile, BK=32, 256 threads = 4 waves, each wave 64x64 (4x4 of 16x16x32 MFMA)
template <typename CT>
__global__ __launch_bounds__(256, 2) void gemm_nt(const bf16* __restrict__ A,
                                                  const bf16* __restrict__ Bt,
                                                  CT* __restrict__ C,
                                                  int M, int N, int K) {
    __shared__ bf16 As[128 * 32];
    __shared__ bf16 Bs[128 * 32];
    const int tid = threadIdx.x;
    const int lane = tid & 63;
    const int quad = lane >> 4;
    const int r16 = lane & 15;
    const int wave = tid >> 6;
    const int bm = blockIdx.y * 128;
    const int bn = blockIdx.x * 128;
    const int wm = (wave >> 1) * 64;
    const int wn = (wave & 1) * 64;

    f32x4 acc[4][4] = {};

    // staging: thread t loads 16B at row (t>>2), k-chunk (t&3)*8; LDS dest linear = t*16B
    const int arow = tid >> 2;
    const int kch = (tid & 3) * 8;
    const bf16* Ap = A + (size_t)(bm + arow) * K + kch;
    const bf16* Bp = Bt + (size_t)(bn + arow) * K + kch;
    bf16* Asd = As + tid * 8;
    bf16* Bsd = Bs + tid * 8;
    const int kq = quad * 8;

    for (int k0 = 0; k0 < K; k0 += 32) {
        __syncthreads();
        gld_lds16(Ap, Asd);
        gld_lds16(Ap + (size_t)64 * K, Asd + 64 * 32);
        gld_lds16(Bp, Bsd);
        gld_lds16(Bp + (size_t)64 * K, Bsd + 64 * 32);
        Ap += 32; Bp += 32;
        __syncthreads();
        short8 af[4], bfr[4];
#pragma unroll
        for (int i = 0; i < 4; i++)
            af[i] = *(const short8*)(As + (wm + i * 16 + r16) * 32 + kq);
#pragma unroll
        for (int j = 0; j < 4; j++)
            bfr[j] = *(const short8*)(Bs + (wn + j * 16 + r16) * 32 + kq);
#pragma unroll
        for (int i = 0; i < 4; i++)
#pragma unroll
            for (int j = 0; j < 4; j++)
                acc[i][j] = __builtin_amdgcn_mfma_f32_16x16x32_bf16(af[i], bfr[j], acc[i][j], 0, 0, 0);
    }
    // epilogue: C/D layout col=lane&15, row=(lane>>4)*4+r   [verified m89/m91]
#pragma unroll
    for (int i = 0; i < 4; i++)
#pragma unroll
        for (int j = 0; j < 4; j++) {
            int row = bm + wm + i * 16 + quad * 4;
            int col = bn + wn + j * 16 + r16;
#pragma unroll
            for (int r = 0; r < 4; r++)
                store_val(C + (size_t)(row + r) * N + col, acc[i][j][r]);
        }
}

// ---------------- RoPE + split + V transpose ----------------
// qkv [4096][3072] bf16 -> qr [4096][2048], kr [4096][512], vt [2][8][64][2048]
__global__ void rope_kernel(const bf16* __restrict__ qkv, const float* __restrict__ fc,
                            bf16* __restrict__ qr, bf16* __restrict__ kr, bf16* __restrict__ vt) {
    int p = blockIdx.x * blockDim.x + threadIdx.x;  // pair index 0..1535
    int row = blockIdx.y;                            // 0..4095
    int s = row & (SEQ - 1);
    int b = row >> 11;
    int col = p * 2;
    const bf16* src = qkv + (size_t)row * QKVD + col;
    float x0 = __bfloat162float(src[0]);
    float x1 = __bfloat162float(src[1]);
    if (col < DIM) {
        int j = (col & 63) >> 1;
        float c = fc[(s * 32 + j) * 2 + 0];
        float sn = fc[(s * 32 + j) * 2 + 1];
        qr[(size_t)row * DIM + col]     = __float2bfloat16(x0 * c - x1 * sn);
        qr[(size_t)row * DIM + col + 1] = __float2bfloat16(x1 * c + x0 * sn);
    } else if (col < DIM + KVD) {
        int ck = col - DIM;
        int j = (ck & 63) >> 1;
        float c = fc[(s * 32 + j) * 2 + 0];
        float sn = fc[(s * 32 + j) * 2 + 1];
        kr[(size_t)row * KVD + ck]     = __float2bfloat16(x0 * c - x1 * sn);
        kr[(size_t)row * KVD + ck + 1] = __float2bfloat16(x1 * c + x0 * sn);
    } else {
        int cv = col - DIM - KVD;
        int kvh = cv >> 6;
        int d = cv & 63;
        size_t base = (((size_t)b * NKV + kvh) * HD + d) * SEQ + s;
        vt[base] = __float2bfloat16(x0);
        vt[base + SEQ] = __float2bfloat16(x1);
    }
}

// ---------------- Flash attention (causal, GQA) ----------------
// 1 wave = one 16-row Q tile; 32-key blocks; no block-wide barriers (divergent trip counts).
__global__ __launch_bounds__(256, 2) void attn_kernel(const bf16* __restrict__ qr,
                                                      const bf16* __restrict__ kr,
                                                      const bf16* __restrict__ vt,
                                                      bf16* __restrict__ out) {
    __shared__ bf16 Pl[4][16][40];  // per-wave P transpose buffer, row stride 80B (16B-aligned)
    const int lane = threadIdx.x & 63;
    const int wv = threadIdx.x >> 6;
    const int quad = lane >> 4;
    const int r16 = lane & 15;
    const int h = blockIdx.y;
    const int b = blockIdx.z;
    const int kvh = h >> 2;
    const int q0 = (blockIdx.x * 4 + wv) * 16;

    const bf16* Qp = qr + ((size_t)b * SEQ) * DIM + (size_t)h * HD;
    const bf16* Kp = kr + ((size_t)b * SEQ) * KVD + (size_t)kvh * HD;
    const bf16* Vp = vt + ((size_t)(b * NKV + kvh)) * HD * SEQ;

    // Q A-fragments: A[m=lane&15][k=quad*8+j], two K=32 chunks covering d=0..63
    short8 qa[2];
#pragma unroll
    for (int c = 0; c < 2; c++)
        qa[c] = *(const short8*)(Qp + (size_t)(q0 + r16) * DIM + c * 32 + quad * 8);

    f32x4 o[4] = {};
    float m_i[4], l_i[4];
#pragma unroll
    for (int r = 0; r < 4; r++) { m_i[r] = -__builtin_inff(); l_i[r] = 0.f; }

    const int nkb = (q0 + 15) / 32 + 1;
    for (int kb = 0; kb < nkb; kb++) {
        const int kbase = kb * 32;
        const f32x4 z = {0.f, 0.f, 0.f, 0.f};
        f32x4 sc[2];
#pragma unroll
        for (int n = 0; n < 2; n++) {
            short8 kf0 = *(const short8*)(Kp + (size_t)(kbase + n * 16 + r16) * KVD + quad * 8);
            short8 kf1 = *(const short8*)(Kp + (size_t)(kbase + n * 16 + r16) * KVD + 32 + quad * 8);
            sc[n] = __builtin_amdgcn_mfma_f32_16x16x32_bf16(qa[0], kf0, z, 0, 0, 0);
            sc[n] = __builtin_amdgcn_mfma_f32_16x16x32_bf16(qa[1], kf1, sc[n], 0, 0, 0);
        }
        float sv[2][4];
        if (kbase + 31 > q0) {  // wave-uniform: only diagonal blocks need the mask
#pragma unroll
            for (int n = 0; n < 2; n++)
#pragma unroll
                for (int r = 0; r < 4; r++) {
                    int kidx = kbase + n * 16 + r16;
                    int qidx = q0 + quad * 4 + r;
                    sv[n][r] = (kidx <= qidx) ? sc[n][r] * 0.125f : -__builtin_inff();
                }
        } else {
#pragma unroll
            for (int n = 0; n < 2; n++)
#pragma unroll
                for (int r = 0; r < 4; r++)
                    sv[n][r] = sc[n][r] * 0.125f;
        }
        // row max over 32 cols: local + 16-lane butterfly (xor 1,2,4,8 stays in quad-group)
        float mx[4];
#pragma unroll
        for (int r = 0; r < 4; r++) mx[r] = fmaxf(sv[0][r], sv[1][r]);
#pragma unroll
        for (int off = 1; off <= 8; off <<= 1)
#pragma unroll
            for (int r = 0; r < 4; r++) mx[r] = fmaxf(mx[r], __shfl_xor(mx[r], off, 64));
        float alpha[4];
#pragma unroll
        for (int r = 0; r < 4; r++) {
            float mn = fmaxf(m_i[r], mx[r]);
            alpha[r] = __expf(m_i[r] - mn);
            m_i[r] = mn;
        }
        float p[2][4];
#pragma unroll
        for (int n = 0; n < 2; n++)
#pragma unroll
            for (int r = 0; r < 4; r++) p[n][r] = __expf(sv[n][r] - m_i[r]);
        float rs[4];
#pragma unroll
        for (int r = 0; r < 4; r++) rs[r] = p[0][r] + p[1][r];
#pragma unroll
        for (int off = 1; off <= 8; off <<= 1)
#pragma unroll
            for (int r = 0; r < 4; r++) rs[r] += __shfl_xor(rs[r], off, 64);
#pragma unroll
        for (int r = 0; r < 4; r++) l_i[r] = l_i[r] * alpha[r] + rs[r];
        // P: C-layout -> A-layout via per-wave LDS (m120 pattern), bf16
#pragma unroll
        for (int n = 0; n < 2; n++)
#pragma unroll
            for (int r = 0; r < 4; r++)
                Pl[wv][quad * 4 + r][n * 16 + r16] = __float2bfloat16(p[n][r]);
        asm volatile("s_waitcnt lgkmcnt(0)" ::: "memory");  // wave-local DS drain
        short8 pf = *(const short8*)&Pl[wv][r16][quad * 8];
        // rescale O, then PV (V from transposed [d][s] layout: contiguous 8 k's)
#pragma unroll
        for (int t = 0; t < 4; t++)
#pragma unroll
            for (int r = 0; r < 4; r++) o[t][r] *= alpha[r];
#pragma unroll
        for (int t = 0; t < 4; t++) {
            short8 vf = *(const short8*)(Vp + (size_t)(t * 16 + r16) * SEQ + kbase + quad * 8);
            o[t] = __builtin_amdgcn_mfma_f32_16x16x32_bf16(pf, vf, o[t], 0, 0, 0);
        }
        asm volatile("" ::: "memory");
    }
    // epilogue: divide by l, store [b][s][h*64+d] bf16
#pragma unroll
    for (int t = 0; t < 4; t++)
#pragma unroll
        for (int r = 0; r < 4; r++) {
            int srow = q0 + quad * 4 + r;
            out[((size_t)b * SEQ + srow) * DIM + (size_t)h * HD + t * 16 + r16] =
                __float2bfloat16(o[t][r] / l_i[r]);
        }
}

extern "C" void kernel_launch(void* const* d_in, const int* in_sizes, int n_in,
                              void* d_out, int out_size, void* d_ws, size_t ws_size,
                              hipStream_t stream) {
    (void)in_sizes; (void)n_in; (void)out_size; (void)ws_size;
    const float* x    = (const float*)d_in[0];
    const float* fc   = (const float*)d_in[1];
    // d_in[2] = mask: known causal tril, not read
    const float* wqkv = (const float*)d_in[3];
    const float* wo   = (const float*)d_in[4];
    float* out = (float*)d_out;

    char* w = (char*)d_ws;
    bf16* xb    = (bf16*)(w);              // 16,777,216 B  (later aliased by qr)
    bf16* wqkvb = (bf16*)(w + 16777216);   // 12,582,912 B
    bf16* wob   = (bf16*)(w + 29360128);   //  8,388,608 B
    bf16* qkvb  = (bf16*)(w + 37748736);   // 25,165,824 B  (later aliased by attnb)
    bf16* kr    = (bf16*)(w + 62914560);   //  4,194,304 B
    bf16* vt    = (bf16*)(w + 67108864);   //  4,194,304 B  -> total 71,303,168 B
    bf16* qr = xb;       // xb dead after GEMM1
    bf16* attnb = qkvb;  // qkvb dead after rope

    cvt_kernel<<<8192, 256, 0, stream>>>(x, xb, 2097152);
    cvt_kernel<<<6144, 256, 0, stream>>>(wqkv, wqkvb, 1572864);
    cvt_kernel<<<4096, 256, 0, stream>>>(wo, wob, 1048576);
    gemm_nt<bf16><<<dim3(24, 32), 256, 0, stream>>>(xb, wqkvb, qkvb, 4096, QKVD, DIM);
    rope_kernel<<<dim3(6, 4096), 256, 0, stream>>>(qkvb, fc, qr, kr, vt);
    attn_kernel<<<dim3(32, NH, 2), 256, 0, stream>>>(qr, kr, vt, attnb);
    gemm_nt<float><<<dim3(16, 32), 256, 0, stream>>>(attnb, wob, out, 4096, DIM, DIM);
}